// Round 5
// baseline (219.540 us; speedup 1.0000x reference)
//
#include <hip/hip_runtime.h>

#define BDIM 256
#define KC_STRIDE 28                  // per (case,co): K[0..24], bias at [25], 2 pad
#define CASE_STRIDE (32 * KC_STRIDE)  // 896 floats per border-case

// case index along one axis: 0 (p==0), 1 (p==1), 2 (interior), 3 (p==62), 4 (p==63)
__device__ __forceinline__ int casef(int p) {
  return ((unsigned)(p - 2) < 60u) ? 2 : (p < 2 ? p : p - 59);
}

// ---------------- prep: collapsed 5x5 kernels, layout [case][co][28] ----------------
__global__ __launch_bounds__(BDIM) void prep_kernel(
    const float* __restrict__ W1, const float* __restrict__ b1,
    const float* __restrict__ W2, const float* __restrict__ b2,
    float* __restrict__ ws) {
  __shared__ float Mlds[9 * 9 * 32];
  __shared__ float BvL[9 * 32];
  const int tid = threadIdx.x;
  const int co = tid & 31;
  for (int tap = tid >> 5; tap < 9; tap += 8) {
    float acc[9] = {0.f, 0.f, 0.f, 0.f, 0.f, 0.f, 0.f, 0.f, 0.f};
    float accB = 0.f;
    for (int ci = 0; ci < 64; ++ci) {
      float w2 = W2[(tap * 64 + ci) * 32 + co];
      accB = fmaf(b1[ci], w2, accB);
#pragma unroll
      for (int e = 0; e < 9; ++e) acc[e] = fmaf(W1[e * 64 + ci], w2, acc[e]);
    }
#pragma unroll
    for (int e = 0; e < 9; ++e) Mlds[(tap * 9 + e) * 32 + co] = acc[e];
    BvL[tap * 32 + co] = accB;
  }
  __syncthreads();

  const int a = blockIdx.x / 5, c = blockIdx.x % 5;
  const int dmask[5] = {4, 6, 7, 3, 1};
  const int Da = dmask[a], Dc = dmask[c];
  for (int t = tid; t < CASE_STRIDE; t += BDIM) {
    int cc = t / KC_STRIDE, r = t % KC_STRIDE;
    float s = 0.f;
    if (r < 25) {
      int u = r / 5, v = r % 5;
      for (int di = 0; di < 3; ++di) {
        if (!((Da >> di) & 1)) continue;
        int ei = u - di;
        if ((unsigned)ei > 2u) continue;
        for (int dj = 0; dj < 3; ++dj) {
          if (!((Dc >> dj) & 1)) continue;
          int ej = v - dj;
          if ((unsigned)ej > 2u) continue;
          s += Mlds[((di * 3 + dj) * 9 + ei * 3 + ej) * 32 + cc];
        }
      }
    } else if (r == 25) {
      s = b2[cc];
      for (int di = 0; di < 3; ++di)
        if ((Da >> di) & 1)
          for (int dj = 0; dj < 3; ++dj)
            if ((Dc >> dj) & 1) s += BvL[(di * 3 + dj) * 32 + cc];
    }
    ws[blockIdx.x * CASE_STRIDE + t] = s;
  }
}

// ---------------- main: barrier-free dense-direct, SGPR kernels, full-line stores ----
__global__ __launch_bounds__(BDIM, 4) void main_kernel(
    const float* __restrict__ x, const float* __restrict__ ws,
    float* __restrict__ out) {
  const int b = blockIdx.x;
  const int tid = threadIdx.x;
  const int lane = tid & 63;
  const int wave = tid >> 6;

  __shared__ __align__(16) float xp[68 * 68];  // x rows -2..65, cols -2..65
  __shared__ unsigned long long Rm[64];
  __shared__ __align__(16) float edge[4][2][60][2][4];  // [wave][coSel][r-2][side][px]

  float4* xp4 = reinterpret_cast<float4*>(xp);
  for (int i = tid; i < 68 * 68 / 4; i += BDIM) xp4[i] = make_float4(0.f, 0.f, 0.f, 0.f);
  __syncthreads();

  const float* xb = x + (size_t)b * 4096;
  for (int it = tid; it < 1024; it += BDIM) {
    int r = it >> 4, c4 = (it & 15) << 2;
    float4 v = *reinterpret_cast<const float4*>(xb + r * 64 + c4);
    float2* d2 = reinterpret_cast<float2*>(&xp[(2 + r) * 68 + 2 + c4]);
    d2[0] = make_float2(v.x, v.y);
    d2[1] = make_float2(v.z, v.w);
  }
  __syncthreads();

  for (int r = wave; r < 64; r += 4) {
    unsigned long long m = __ballot(xp[(2 + r) * 68 + 2 + lane] != 0.0f);
    if (lane == 0) Rm[r] = m;
  }
  __syncthreads();

  float* outb = out + (size_t)b * (32 * 4096);

  for (int ci = 0; ci < 4; ++ci) {
    const int cu0 = __builtin_amdgcn_readfirstlane(wave + (ci << 3));
    const int cu1 = cu0 + 4;
    // interior (case 2,2) kernels -> SGPRs (uniform address)
    const float* KaP = ws + 12 * CASE_STRIDE + cu0 * KC_STRIDE;
    const float* KbP = ws + 12 * CASE_STRIDE + cu1 * KC_STRIDE;
    float KA[26], KB[26];
#pragma unroll
    for (int j = 0; j < 26; ++j) { KA[j] = KaP[j]; KB[j] = KbP[j]; }

    // ---- phase C: column-border quads (rows 2..61) -> edge LDS (same wave) ----
#pragma unroll
    for (int side = 0; side < 2; ++side) {
      if (lane < 60) {
        const int p = 2 + lane;
        const int q0 = side ? 60 : 0;
        unsigned bits = (unsigned)(Rm[p] >> q0) & 0xFu;
        const int ja = side ? 2 : 0, jb = side ? 3 : 1;    // special px
        const int ji0 = side ? 0 : 2, ji1 = side ? 1 : 3;  // interior px
        const int ca = side ? 3 : 0, cb = side ? 4 : 1;
        const float* Pa0 = ws + ((10 + ca) * 32 + cu0) * KC_STRIDE;
        const float* Pb0 = ws + ((10 + cb) * 32 + cu0) * KC_STRIDE;
        const float* Pa1 = ws + ((10 + ca) * 32 + cu1) * KC_STRIDE;
        const float* Pb1 = ws + ((10 + cb) * 32 + cu1) * KC_STRIDE;
        float zsA0 = Pa0[25], zsB0 = Pb0[25], zsA1 = Pa1[25], zsB1 = Pb1[25];
        float ziA0 = KA[25], ziB0 = KA[25], ziA1 = KB[25], ziB1 = KB[25];
#pragma unroll
        for (int u = 0; u < 5; ++u) {
          float4 xa = *reinterpret_cast<const float4*>(&xp[(p + u) * 68 + q0]);
          float4 xc = *reinterpret_cast<const float4*>(&xp[(p + u) * 68 + q0 + 4]);
          float xv[8] = {xa.x, xa.y, xa.z, xa.w, xc.x, xc.y, xc.z, xc.w};
#pragma unroll
          for (int v = 0; v < 5; ++v) {
            const int o = u * 5 + v;
            zsA0 = fmaf(xv[v + ja], Pa0[o], zsA0);
            zsB0 = fmaf(xv[v + jb], Pb0[o], zsB0);
            zsA1 = fmaf(xv[v + ja], Pa1[o], zsA1);
            zsB1 = fmaf(xv[v + jb], Pb1[o], zsB1);
            float k0 = KA[o], k1 = KB[o];
            ziA0 = fmaf(xv[v + ji0], k0, ziA0);
            ziB0 = fmaf(xv[v + ji1], k0, ziB0);
            ziA1 = fmaf(xv[v + ji0], k1, ziA1);
            ziB1 = fmaf(xv[v + ji1], k1, ziB1);
          }
        }
        float o0[4], o1[4];
        if (side == 0) {
          o0[0] = zsA0; o0[1] = zsB0; o0[2] = ziA0; o0[3] = ziB0;
          o1[0] = zsA1; o1[1] = zsB1; o1[2] = ziA1; o1[3] = ziB1;
        } else {
          o0[0] = ziA0; o0[1] = ziB0; o0[2] = zsA0; o0[3] = zsB0;
          o1[0] = ziA1; o1[1] = ziB1; o1[2] = zsA1; o1[3] = zsB1;
        }
        if (!(bits & 1u)) { o0[0] = 0.f; o1[0] = 0.f; }
        if (!(bits & 2u)) { o0[1] = 0.f; o1[1] = 0.f; }
        if (!(bits & 4u)) { o0[2] = 0.f; o1[2] = 0.f; }
        if (!(bits & 8u)) { o0[3] = 0.f; o1[3] = 0.f; }
        *reinterpret_cast<float4*>(&edge[wave][0][lane][side][0]) =
            make_float4(o0[0], o0[1], o0[2], o0[3]);
        *reinterpret_cast<float4*>(&edge[wave][1][lane][side][0]) =
            make_float4(o1[0], o1[1], o1[2], o1[3]);
      }
    }

    // ---- phase A: rows 2..61, SGPR kernels; border quads pulled from edge LDS ----
    const int r = lane >> 4, qq = lane & 15;
    const int q0 = qq << 2;
    for (int rg = 0; rg < 15; ++rg) {
      const int p = 2 + (rg << 2) + r;
      unsigned bits = (unsigned)(Rm[p] >> q0) & 0xFu;
      float4 va, vb;
      if ((unsigned)(qq - 1) < 14u) {
        float z0a = KA[25], z1a = KA[25], z2a = KA[25], z3a = KA[25];
        float z0b = KB[25], z1b = KB[25], z2b = KB[25], z3b = KB[25];
#pragma unroll
        for (int u = 0; u < 5; ++u) {
          float4 xa = *reinterpret_cast<const float4*>(&xp[(p + u) * 68 + q0]);
          float4 xc = *reinterpret_cast<const float4*>(&xp[(p + u) * 68 + q0 + 4]);
          float xv[8] = {xa.x, xa.y, xa.z, xa.w, xc.x, xc.y, xc.z, xc.w};
#pragma unroll
          for (int v = 0; v < 5; ++v) {
            float k0 = KA[u * 5 + v], k1 = KB[u * 5 + v];
            z0a = fmaf(xv[v], k0, z0a);
            z1a = fmaf(xv[v + 1], k0, z1a);
            z2a = fmaf(xv[v + 2], k0, z2a);
            z3a = fmaf(xv[v + 3], k0, z3a);
            z0b = fmaf(xv[v], k1, z0b);
            z1b = fmaf(xv[v + 1], k1, z1b);
            z2b = fmaf(xv[v + 2], k1, z2b);
            z3b = fmaf(xv[v + 3], k1, z3b);
          }
        }
        if (!(bits & 1u)) { z0a = 0.f; z0b = 0.f; }
        if (!(bits & 2u)) { z1a = 0.f; z1b = 0.f; }
        if (!(bits & 4u)) { z2a = 0.f; z2b = 0.f; }
        if (!(bits & 8u)) { z3a = 0.f; z3b = 0.f; }
        va = make_float4(z0a, z1a, z2a, z3a);
        vb = make_float4(z0b, z1b, z2b, z3b);
      } else {
        const int side = qq ? 1 : 0;
        va = *reinterpret_cast<const float4*>(&edge[wave][0][p - 2][side][0]);
        vb = *reinterpret_cast<const float4*>(&edge[wave][1][p - 2][side][0]);
      }
      *reinterpret_cast<float4*>(outb + (((size_t)cu0) << 12) + (p << 6) + q0) = va;
      *reinterpret_cast<float4*>(outb + (((size_t)cu1) << 12) + (p << 6) + q0) = vb;
    }

    // ---- phase B: border rows 0,1,62,63 (full lines from one wave store) ----
    {
      const int p = (r < 2) ? r : r + 60;
      const int cp = (r < 2) ? r : r + 1;
      unsigned bits = (unsigned)(Rm[p] >> q0) & 0xFu;
      const int c0 = casef(q0), c1 = casef(q0 + 1), c2 = casef(q0 + 2), c3 = casef(q0 + 3);
      const float* P0a = ws + ((cp * 5 + c0) * 32 + cu0) * KC_STRIDE;
      const float* P1a = ws + ((cp * 5 + c1) * 32 + cu0) * KC_STRIDE;
      const float* P2a = ws + ((cp * 5 + c2) * 32 + cu0) * KC_STRIDE;
      const float* P3a = ws + ((cp * 5 + c3) * 32 + cu0) * KC_STRIDE;
      const float* P0b = ws + ((cp * 5 + c0) * 32 + cu1) * KC_STRIDE;
      const float* P1b = ws + ((cp * 5 + c1) * 32 + cu1) * KC_STRIDE;
      const float* P2b = ws + ((cp * 5 + c2) * 32 + cu1) * KC_STRIDE;
      const float* P3b = ws + ((cp * 5 + c3) * 32 + cu1) * KC_STRIDE;
      float z0a = P0a[25], z1a = P1a[25], z2a = P2a[25], z3a = P3a[25];
      float z0b = P0b[25], z1b = P1b[25], z2b = P2b[25], z3b = P3b[25];
#pragma unroll
      for (int u = 0; u < 5; ++u) {
        float4 xa = *reinterpret_cast<const float4*>(&xp[(p + u) * 68 + q0]);
        float4 xc = *reinterpret_cast<const float4*>(&xp[(p + u) * 68 + q0 + 4]);
        float xv[8] = {xa.x, xa.y, xa.z, xa.w, xc.x, xc.y, xc.z, xc.w};
#pragma unroll
        for (int v = 0; v < 5; ++v) {
          const int o = u * 5 + v;
          z0a = fmaf(xv[v], P0a[o], z0a);
          z1a = fmaf(xv[v + 1], P1a[o], z1a);
          z2a = fmaf(xv[v + 2], P2a[o], z2a);
          z3a = fmaf(xv[v + 3], P3a[o], z3a);
          z0b = fmaf(xv[v], P0b[o], z0b);
          z1b = fmaf(xv[v + 1], P1b[o], z1b);
          z2b = fmaf(xv[v + 2], P2b[o], z2b);
          z3b = fmaf(xv[v + 3], P3b[o], z3b);
        }
      }
      if (!(bits & 1u)) { z0a = 0.f; z0b = 0.f; }
      if (!(bits & 2u)) { z1a = 0.f; z1b = 0.f; }
      if (!(bits & 4u)) { z2a = 0.f; z2b = 0.f; }
      if (!(bits & 8u)) { z3a = 0.f; z3b = 0.f; }
      *reinterpret_cast<float4*>(outb + (((size_t)cu0) << 12) + (p << 6) + q0) =
          make_float4(z0a, z1a, z2a, z3a);
      *reinterpret_cast<float4*>(outb + (((size_t)cu1) << 12) + (p << 6) + q0) =
          make_float4(z0b, z1b, z2b, z3b);
    }
  }
}

extern "C" void kernel_launch(void* const* d_in, const int* in_sizes, int n_in,
                              void* d_out, int out_size, void* d_ws, size_t ws_size,
                              hipStream_t stream) {
  const float* x  = (const float*)d_in[0];
  const float* W1 = (const float*)d_in[1];
  const float* b1 = (const float*)d_in[2];
  const float* W2 = (const float*)d_in[3];
  const float* b2 = (const float*)d_in[4];
  float* out = (float*)d_out;
  float* ws  = (float*)d_ws;
  int B = in_sizes[0] / 4096;  // 1024 images of 64x64x1

  hipLaunchKernelGGL(prep_kernel, dim3(25), dim3(BDIM), 0, stream, W1, b1, W2, b2, ws);
  hipLaunchKernelGGL(main_kernel, dim3(B), dim3(BDIM), 0, stream, x, ws, out);
}